// Round 7
// baseline (193.509 us; speedup 1.0000x reference)
//
#include <hip/hip_runtime.h>
#include <math.h>

typedef __bf16 bf16;
typedef bf16 bf16x8 __attribute__((ext_vector_type(8)));
typedef bf16 bf16x4 __attribute__((ext_vector_type(4)));
typedef float f32x4 __attribute__((ext_vector_type(4)));
typedef float f32x16 __attribute__((ext_vector_type(16)));

#define B_ 4
#define L_ 2048
#define D_ 1024
#define H_ 16
#define A_ 64
#define HA_ 1024
#define BL_ 8192
#define LOG2E 1.44269504088896340736f

__device__ __forceinline__ void gload16(const void* g, void* l) {
  __builtin_amdgcn_global_load_lds((const __attribute__((address_space(1))) void*)g,
                                   (__attribute__((address_space(3))) void*)l,
                                   16, 0, 0);
}

__device__ __forceinline__ unsigned cvt_pk_bf16(float lo, float hi) {
  unsigned r;
  asm volatile("v_cvt_pk_bf16_f32 %0, %1, %2" : "=v"(r) : "v"(lo), "v"(hi));
  return r;
}

// swap halves: new_a[32:63]=old_b[0:31]; new_b[0:31]=old_a[32:63]
// Operands MUST be distinct SSA defs (round-2 lesson).
__device__ __forceinline__ void permswap(unsigned& a, unsigned& b) {
  asm volatile("v_permlane32_swap_b32 %0, %1" : "+v"(a), "+v"(b));
}

// After call: {o1,o2} = {own value, partner(lane^32) value}. v_mov forces a
// distinct SSA def so the two swap operands get distinct physical regs.
__device__ __forceinline__ void half_pair(float x, float& o1, float& o2) {
  unsigned a = __builtin_bit_cast(unsigned, x), b;
  asm volatile("v_mov_b32 %0, %1" : "=v"(b) : "v"(a));
  asm volatile("v_permlane32_swap_b32 %0, %1" : "+v"(a), "+v"(b));
  o1 = __builtin_bit_cast(float, a);
  o2 = __builtin_bit_cast(float, b);
}

// ---------------- fused cast f32 -> bf16 for xq, xkv, Ow (one launch) ----------------
__global__ __launch_bounds__(256) void cast_all(const float* __restrict__ xq,
                                                const float* __restrict__ xkv,
                                                const float* __restrict__ ow,
                                                bf16* __restrict__ xq_b,
                                                bf16* __restrict__ xkv_b,
                                                bf16* __restrict__ wo_b) {
  const int NX = BL_ * D_ / 8;   // 1048576
  const int NW = D_ * HA_ / 8;   // 131072
  int i = blockIdx.x * blockDim.x + threadIdx.x;
  const float* src;
  bf16* dst;
  int j;
  if (i < NX) { src = xq; dst = xq_b; j = i; }
  else if (i < 2 * NX) { src = xkv; dst = xkv_b; j = i - NX; }
  else if (i < 2 * NX + NW) { src = ow; dst = wo_b; j = i - 2 * NX; }
  else return;
  const float4* s = reinterpret_cast<const float4*>(src) + (size_t)j * 2;
  float4 a = s[0], b = s[1];
  bf16x8 o;
  o[0] = (bf16)a.x; o[1] = (bf16)a.y; o[2] = (bf16)a.z; o[3] = (bf16)a.w;
  o[4] = (bf16)b.x; o[5] = (bf16)b.y; o[6] = (bf16)b.z; o[7] = (bf16)b.w;
  *reinterpret_cast<bf16x8*>(dst + (size_t)j * 8) = o;
}

// ------- transpose+cast 3 weights: in [D][HA] f32 -> out [HA][D] bf16 (z picks which) -------
__global__ __launch_bounds__(256) void transpose_cast_w3(const float* __restrict__ wq,
                                                         const float* __restrict__ wk,
                                                         const float* __restrict__ wv,
                                                         bf16* __restrict__ oq,
                                                         bf16* __restrict__ ok,
                                                         bf16* __restrict__ ov) {
  __shared__ float tile[32][33];
  const int z = blockIdx.z;
  const float* w = (z == 0) ? wq : (z == 1) ? wk : wv;
  bf16* wt = (z == 0) ? oq : (z == 1) ? ok : ov;
  const float scale = (z == 0) ? LOG2E : 1.0f;  // fold log2e into Q
  const int d0 = blockIdx.y * 32, h0 = blockIdx.x * 32;
  const int tx = threadIdx.x, ty = threadIdx.y;  // (32,8)
  #pragma unroll
  for (int j = 0; j < 4; j++)
    tile[ty + j * 8][tx] = w[(size_t)(d0 + ty + j * 8) * HA_ + h0 + tx];
  __syncthreads();
  #pragma unroll
  for (int j = 0; j < 4; j++)
    wt[(size_t)(h0 + ty + j * 8) * D_ + d0 + tx] = (bf16)(tile[tx][ty + j * 8] * scale);
}

// ------------- B^T GEMM core: C[M,N] = A[M,K] * B[N,K]^T, M=8192 N=1024 K=1024 -------------
// MODE 0: bf16 into (B,H,L,A); MODE 1: f32 row-major [M,N]; MODE 2: bf16 V^T (B,H,A,L)
template <int MODE>
__device__ __forceinline__ void gemm_bt_core(const bf16* __restrict__ Ap,
                                             const bf16* __restrict__ Bp,
                                             void* __restrict__ Cp,
                                             int m0, int n0) {
  const int K = 1024;
  __shared__ __align__(16) bf16 As[128 * 32];
  __shared__ __align__(16) bf16 Bs[128 * 32];
  const int tid = threadIdx.x;
  const int lane = tid & 63, w = tid >> 6;
  const int wr = w >> 1, wc = w & 1;
  const int g = lane >> 4, c = lane & 15;
  f32x4 acc[4][4] = {};
  const int srow = tid >> 2, sch = tid & 3;
  const int sw0 = (sch ^ (srow & 3)) * 8;
  for (int k0 = 0; k0 < K; k0 += 32) {
    gload16(Ap + (size_t)(m0 + srow) * K + k0 + sw0, As + tid * 8);
    gload16(Ap + (size_t)(m0 + 64 + srow) * K + k0 + sw0, As + (256 + tid) * 8);
    gload16(Bp + (size_t)(n0 + srow) * K + k0 + sw0, Bs + tid * 8);
    gload16(Bp + (size_t)(n0 + 64 + srow) * K + k0 + sw0, Bs + (256 + tid) * 8);
    __syncthreads();
    bf16x8 af[4], bfr[4];
    #pragma unroll
    for (int m = 0; m < 4; m++)
      af[m] = *reinterpret_cast<const bf16x8*>(As + (wr * 64 + m * 16 + c) * 32 + ((g ^ (c & 3)) * 8));
    #pragma unroll
    for (int n = 0; n < 4; n++)
      bfr[n] = *reinterpret_cast<const bf16x8*>(Bs + (wc * 64 + n * 16 + c) * 32 + ((g ^ (c & 3)) * 8));
    #pragma unroll
    for (int m = 0; m < 4; m++)
      #pragma unroll
      for (int n = 0; n < 4; n++)
        acc[m][n] = __builtin_amdgcn_mfma_f32_16x16x32_bf16(af[m], bfr[n], acc[m][n], 0, 0, 0);
    __syncthreads();
  }
  #pragma unroll
  for (int m = 0; m < 4; m++) {
    #pragma unroll
    for (int n = 0; n < 4; n++) {
      if (MODE == 2) {
        // V^T write: 4 consecutive l at fixed (b,h,a)
        int row0 = m0 + wr * 64 + m * 16 + g * 4;
        int col = n0 + wc * 64 + n * 16 + c;
        int b = row0 >> 11, l0 = row0 & 2047, h = col >> 6, a = col & 63;
        bf16x4 o4;
        #pragma unroll
        for (int i = 0; i < 4; i++) o4[i] = (bf16)acc[m][n][i];
        *reinterpret_cast<bf16x4*>((bf16*)Cp + ((size_t)(b * H_ + h) * A_ + a) * L_ + l0) = o4;
      } else {
        #pragma unroll
        for (int i = 0; i < 4; i++) {
          int row = m0 + wr * 64 + m * 16 + g * 4 + i;
          int col = n0 + wc * 64 + n * 16 + c;
          float v = acc[m][n][i];
          if (MODE == 0) {
            int b = row >> 11, l = row & 2047, h = col >> 6, a = col & 63;
            ((bf16*)Cp)[(((size_t)b * H_ + h) * L_ + l) * A_ + a] = (bf16)v;
          } else {
            ((float*)Cp)[(size_t)row * 1024 + col] = v;
          }
        }
      }
    }
  }
}

// XCD remap: 512 blocks -> xcd = id&7 owns an 8-mblk x 8-nblk patch
__device__ __forceinline__ void xcd_mn(int id, int& m0, int& n0) {
  int xcd = id & 7, j = id >> 3;
  m0 = (xcd * 8 + (j >> 3)) * 128;
  n0 = (j & 7) * 128;
}

__global__ __launch_bounds__(256, 2) void gemm_proj(const bf16* xq_b, const bf16* xkv_b,
                                                    const bf16* wq, const bf16* wk, const bf16* wv,
                                                    bf16* qb, bf16* kb, bf16* vtb) {
  int m0, n0;
  xcd_mn(blockIdx.x, m0, n0);
  const int z = blockIdx.z;
  if (z == 0)      gemm_bt_core<0>(xq_b, wq, qb, m0, n0);
  else if (z == 1) gemm_bt_core<0>(xkv_b, wk, kb, m0, n0);
  else             gemm_bt_core<2>(xkv_b, wv, vtb, m0, n0);
}

__global__ __launch_bounds__(256, 2) void gemm_out_k(const bf16* ctx, const bf16* wo, float* out) {
  int m0, n0;
  xcd_mn(blockIdx.x, m0, n0);
  gemm_bt_core<1>(ctx, wo, out, m0, n0);
}

// build two PV B-fragments (16-k slices) from one 32-k score block
// s[r] = P[q=lane&31][k = (r&3) + 8*(r>>2) + 4*hi], hi=lane>>5
__device__ __forceinline__ void pa_build(const f32x16& s, bf16x8& f0, bf16x8& f1) {
  #pragma unroll
  for (int sl = 0; sl < 2; sl++) {
    unsigned a0 = cvt_pk_bf16(s[8 * sl + 0], s[8 * sl + 1]);
    unsigned b0 = cvt_pk_bf16(s[8 * sl + 4], s[8 * sl + 5]);
    permswap(a0, b0);  // word0 = a0, word2 = b0
    unsigned a1 = cvt_pk_bf16(s[8 * sl + 2], s[8 * sl + 3]);
    unsigned b1 = cvt_pk_bf16(s[8 * sl + 6], s[8 * sl + 7]);
    permswap(a1, b1);  // word1 = a1, word3 = b1
    uint4 v; v.x = a0; v.y = a1; v.z = b0; v.w = b1;
    if (sl == 0) f0 = __builtin_bit_cast(bf16x8, v);
    else         f1 = __builtin_bit_cast(bf16x8, v);
  }
}

// ---- flash attention, 4 warps x 64 q-rows each (fat waves, K/V reads feed 2 MFMAs) ----
// No max-subtraction (scores in log2 domain, |s| <~ 64 fits f32 exponent range).
// q(B,H,L,A) [pre-scaled by log2e], k(B,H,L,A), vT(B,H,A,L) -> ctx(B,L,H,A)
// Grid: x = bh (same-XCD blocks share K/V), y = q-block of 256 rows.
__global__ __launch_bounds__(256, 2) void attn_kernel(const bf16* __restrict__ qg,
                                                      const bf16* __restrict__ kg,
                                                      const bf16* __restrict__ vtg,
                                                      bf16* __restrict__ ctx) {
  __shared__ __align__(16) bf16 Ks[2][64 * 64];
  __shared__ __align__(16) bf16 Vs[2][64 * 64];
  const int tid = threadIdx.x;
  const int lane = tid & 63;
  const int w = tid >> 6;       // 0..3
  const int c = lane & 31;
  const int hi = lane >> 5;     // 0/1
  const int cs7 = c & 7;
  const int bh = blockIdx.x;
  const int q0 = blockIdx.y * 256;
  const bf16* qh = qg + (size_t)bh * L_ * A_;
  const bf16* kh = kg + (size_t)bh * L_ * A_;
  const bf16* vh = vtg + (size_t)bh * A_ * L_;

  // two q-row sets per wave: lo = q0+w*64+c, hi = lo+32
  const int qrowL = q0 + w * 64 + c;
  const int qrowH = qrowL + 32;
  bf16x8 qfL[4], qfH[4];
  #pragma unroll
  for (int ds = 0; ds < 4; ds++) {
    qfL[ds] = *reinterpret_cast<const bf16x8*>(qh + (size_t)qrowL * A_ + ds * 16 + hi * 8);
    qfH[ds] = *reinterpret_cast<const bf16x8*>(qh + (size_t)qrowH * A_ + ds * 16 + hi * 8);
  }

  f32x16 oA0 = {}, oA1 = {};  // q-lo: O^T[a<32 | a>=32][q=c]
  f32x16 oB0 = {}, oB1 = {};  // q-hi
  float lrunL = 0.f, lrunH = 0.f;

  // loop-invariant LDS element offsets (K and V share the same geometry)
  int koA[4], koB[4];
  #pragma unroll
  for (int ds = 0; ds < 4; ds++) {
    koA[ds] = c * 64 + ((2 * ds + hi) ^ cs7) * 8;
    koB[ds] = (32 + c) * 64 + ((2 * ds + hi) ^ cs7) * 8;
  }

  // staging: 256 threads x 4 gload16 = 16KB (K rows sr, sr+32; V rows sr, sr+32)
  const int sr = tid >> 3, sc = tid & 7;
  const int ss = (sc ^ (sr & 7)) * 8;  // pre-swizzled source -> LDS holds swizzled rows
  const bf16* ksrc0 = kh + (size_t)sr * A_ + ss;
  const bf16* ksrc1 = kh + (size_t)(sr + 32) * A_ + ss;
  const bf16* vsrc0 = vh + (size_t)sr * L_ + ss;
  const bf16* vsrc1 = vh + (size_t)(sr + 32) * L_ + ss;

  auto stage = [&](int buf, int t) {
    gload16(ksrc0 + (size_t)t * 4096, &Ks[buf][tid * 8]);
    gload16(ksrc1 + (size_t)t * 4096, &Ks[buf][2048 + tid * 8]);
    gload16(vsrc0 + (size_t)t * 64, &Vs[buf][tid * 8]);
    gload16(vsrc1 + (size_t)t * 64, &Vs[buf][2048 + tid * 8]);
  };

  stage(0, 0);
  __syncthreads();
  int cur = 0;

  for (int t = 0; t < L_ / 64; t++) {
    if (t < L_ / 64 - 1) stage(cur ^ 1, t + 1);
    const bf16* Kc = Ks[cur];
    const bf16* Vc = Vs[cur];

    // QK^T swapped: each K fragment feeds 2 MFMAs (q-lo, q-hi)
    f32x16 sA0 = {}, sA1 = {}, sB0 = {}, sB1 = {};
    __builtin_amdgcn_s_setprio(1);
    #pragma unroll
    for (int ds = 0; ds < 4; ds++) {
      bf16x8 k0 = *reinterpret_cast<const bf16x8*>(Kc + koA[ds]);
      bf16x8 k1 = *reinterpret_cast<const bf16x8*>(Kc + koB[ds]);
      sA0 = __builtin_amdgcn_mfma_f32_32x32x16_bf16(k0, qfL[ds], sA0, 0, 0, 0);
      sA1 = __builtin_amdgcn_mfma_f32_32x32x16_bf16(k1, qfL[ds], sA1, 0, 0, 0);
      sB0 = __builtin_amdgcn_mfma_f32_32x32x16_bf16(k0, qfH[ds], sB0, 0, 0, 0);
      sB1 = __builtin_amdgcn_mfma_f32_32x32x16_bf16(k1, qfH[ds], sB1, 0, 0, 0);
    }
    __builtin_amdgcn_s_setprio(0);

    // p = exp2(s_raw)
    #pragma unroll
    for (int r = 0; r < 16; r++) {
      sA0[r] = __builtin_amdgcn_exp2f(sA0[r]);
      sA1[r] = __builtin_amdgcn_exp2f(sA1[r]);
      sB0[r] = __builtin_amdgcn_exp2f(sB0[r]);
      sB1[r] = __builtin_amdgcn_exp2f(sB1[r]);
    }

    // denominators: in-lane tree + cross-half permlane
    {
      float u0[8], v0[8];
      #pragma unroll
      for (int r = 0; r < 8; r++) {
        u0[r] = (sA0[r] + sA0[r + 8]) + (sA1[r] + sA1[r + 8]);
        v0[r] = (sB0[r] + sB0[r + 8]) + (sB1[r] + sB1[r + 8]);
      }
      float us = ((u0[0] + u0[1]) + (u0[2] + u0[3])) + ((u0[4] + u0[5]) + (u0[6] + u0[7]));
      float vs = ((v0[0] + v0[1]) + (v0[2] + v0[3])) + ((v0[4] + v0[5]) + (v0[6] + v0[7]));
      float y1, y2, z1, z2;
      half_pair(us, y1, y2);
      half_pair(vs, z1, z2);
      lrunL += y1 + y2;
      lrunH += z1 + z2;
    }

    // P -> bf16 B-fragments in-register (T12)
    bf16x8 paA0, paA1, paA2, paA3, paB0, paB1, paB2, paB3;
    pa_build(sA0, paA0, paA1);
    pa_build(sA1, paA2, paA3);
    pa_build(sB0, paB0, paB1);
    pa_build(sB1, paB2, paB3);

    // PV swapped: each V fragment feeds 2 MFMAs
    __builtin_amdgcn_s_setprio(1);
    #pragma unroll
    for (int ks = 0; ks < 4; ks++) {
      const bf16x8 pa = (ks == 0) ? paA0 : (ks == 1) ? paA1 : (ks == 2) ? paA2 : paA3;
      const bf16x8 pb = (ks == 0) ? paB0 : (ks == 1) ? paB1 : (ks == 2) ? paB2 : paB3;
      bf16x8 v0 = *reinterpret_cast<const bf16x8*>(Vc + koA[ks]);
      bf16x8 v1 = *reinterpret_cast<const bf16x8*>(Vc + koB[ks]);
      oA0 = __builtin_amdgcn_mfma_f32_32x32x16_bf16(v0, pa, oA0, 0, 0, 0);
      oA1 = __builtin_amdgcn_mfma_f32_32x32x16_bf16(v1, pa, oA1, 0, 0, 0);
      oB0 = __builtin_amdgcn_mfma_f32_32x32x16_bf16(v0, pb, oB0, 0, 0, 0);
      oB1 = __builtin_amdgcn_mfma_f32_32x32x16_bf16(v1, pb, oB1, 0, 0, 0);
    }
    __builtin_amdgcn_s_setprio(0);

    __syncthreads();
    cur ^= 1;
  }

  // normalize + write ctx(B,L,H,A); a = (reg&3)+8*(reg>>2)+4hi+32n
  const int b = bh >> 4, h = bh & 15;
  {
    float inv = 1.f / lrunL;
    bf16* crow = ctx + (((size_t)b * L_ + qrowL) * H_ + h) * A_;
    #pragma unroll
    for (int n = 0; n < 2; n++)
      #pragma unroll
      for (int rq = 0; rq < 4; rq++) {
        bf16x4 o4;
        #pragma unroll
        for (int j = 0; j < 4; j++) {
          float v = (n == 0) ? oA0[rq * 4 + j] : oA1[rq * 4 + j];
          o4[j] = (bf16)(v * inv);
        }
        *reinterpret_cast<bf16x4*>(crow + n * 32 + rq * 8 + hi * 4) = o4;
      }
  }
  {
    float inv = 1.f / lrunH;
    bf16* crow = ctx + (((size_t)b * L_ + qrowH) * H_ + h) * A_;
    #pragma unroll
    for (int n = 0; n < 2; n++)
      #pragma unroll
      for (int rq = 0; rq < 4; rq++) {
        bf16x4 o4;
        #pragma unroll
        for (int j = 0; j < 4; j++) {
          float v = (n == 0) ? oB0[rq * 4 + j] : oB1[rq * 4 + j];
          o4[j] = (bf16)(v * inv);
        }
        *reinterpret_cast<bf16x4*>(crow + n * 32 + rq * 8 + hi * 4) = o4;
      }
  }
}

extern "C" void kernel_launch(void* const* d_in, const int* in_sizes, int n_in,
                              void* d_out, int out_size, void* d_ws, size_t ws_size,
                              hipStream_t stream) {
  const float* xq = (const float*)d_in[0];
  const float* xkv = (const float*)d_in[1];
  const float* Qw = (const float*)d_in[2];
  const float* Kw = (const float*)d_in[3];
  const float* Vw = (const float*)d_in[4];
  const float* Ow = (const float*)d_in[5];
  float* out = (float*)d_out;

  char* ws = (char*)d_ws;
  const size_t SZ16 = (size_t)BL_ * HA_ * sizeof(bf16);  // 16 MiB
  const size_t SZW = (size_t)D_ * HA_ * sizeof(bf16);    // 2 MiB
  bf16* xq_b = (bf16*)(ws);
  bf16* xkv_b = (bf16*)(ws + SZ16);     // later reused as ctx
  bf16* wq_t = (bf16*)(ws + 2 * SZ16);
  bf16* wk_t = (bf16*)(ws + 2 * SZ16 + SZW);
  bf16* wv_t = (bf16*)(ws + 2 * SZ16 + 2 * SZW);
  bf16* wo_b = (bf16*)(ws + 2 * SZ16 + 3 * SZW);
  bf16* qb = (bf16*)(ws + 2 * SZ16 + 4 * SZW);
  bf16* kb = qb + (size_t)BL_ * HA_;
  bf16* vtb = kb + (size_t)BL_ * HA_;   // V^T written directly by gemm_proj
  bf16* ctxb = xkv_b;                   // alias: xkv_b dead after gemm_proj

  const int NCAST = (2 * BL_ * D_ + D_ * HA_) / 8;
  cast_all<<<(NCAST + 255) / 256, 256, 0, stream>>>(xq, xkv, Ow, xq_b, xkv_b, wo_b);
  transpose_cast_w3<<<dim3(32, 32, 3), dim3(32, 8), 0, stream>>>(Qw, Kw, Vw, wq_t, wk_t, wv_t);

  gemm_proj<<<dim3(512, 1, 3), 256, 0, stream>>>(xq_b, xkv_b, wq_t, wk_t, wv_t, qb, kb, vtb);
  attn_kernel<<<dim3(64, 8), 256, 0, stream>>>(qb, kb, vtb, ctxb);
  gemm_out_k<<<512, 256, 0, stream>>>(ctxb, wo_b, out);
}